// Round 4
// baseline (244.089 us; speedup 1.0000x reference)
//
#include <hip/hip_runtime.h>
#include <stdint.h>

#define M_ROWS 65536
#define C_DIM  256
#define K_CLS  20
#define P_POS  2048
#define MARGIN_F 0.3f
#define EPS_D (0.0001f / 256.0f)
#define SCALE1 0x7F7F7F7Fu   /* e8m0 127 = 2^0 in all four bytes */
#define SCALE2 0x80808080u   /* e8m0 128 = 2^1 in all four bytes (A operand) */

typedef float floatx4 __attribute__((ext_vector_type(4)));
typedef int   intx8   __attribute__((ext_vector_type(8)));
union Frag8 { intx8 v; uint4 q[2]; };

// async 16B/lane global -> LDS (wave-uniform LDS base + lane*16)
__device__ __forceinline__ void async_copy16(const void* g, void* l) {
    __builtin_amdgcn_global_load_lds(
        (const __attribute__((address_space(1))) void*)g,
        (__attribute__((address_space(3))) void*)l, 16, 0, 0);
}
__device__ __forceinline__ float sigm(float x) { return 1.f / (1.f + __expf(-x)); }

// flip fp8 e4m3 signs (sign-magnitude; sigmoid outputs have no NaN/Inf)
__device__ __forceinline__ void negA(Frag8& f) {
#pragma unroll
    for (int t = 0; t < 8; ++t) f.v[t] ^= (int)0x80808080u;
}

// ------- Kernel 1: sigmoid -> fp8 e4m3 table + fp8-exact row norms ----------
__global__ __launch_bounds__(256) void sigmoid_norm_k(
        const float* __restrict__ feat,
        unsigned int* __restrict__ S8,     // [M][64] uint = 256 fp8/row
        float* __restrict__ xx,
        unsigned int* __restrict__ hp,
        unsigned int* __restrict__ hn) {
    {
        const int idx = blockIdx.x * 256 + threadIdx.x;
        if (idx < K_CLS * P_POS) { hp[idx] = 0u; hn[idx] = 0xFFFFFFFFu; }
    }
    const int wave = threadIdx.x >> 6, lane = threadIdx.x & 63;
    const int row = blockIdx.x * 4 + wave;
    const float4 v = *(const float4*)(feat + (size_t)row * C_DIM + lane * 4);

    const int p01 = __builtin_amdgcn_cvt_pk_fp8_f32(sigm(v.x), sigm(v.y), 0, false);
    const int p23 = __builtin_amdgcn_cvt_pk_fp8_f32(sigm(v.z), sigm(v.w), 0, false);
    const unsigned int packed = (unsigned int)(p01 & 0xFFFF) | ((unsigned int)p23 << 16);
    S8[(size_t)row * 64 + lane] = packed;

    const float q0 = __builtin_amdgcn_cvt_f32_fp8(p01, 0);
    const float q1 = __builtin_amdgcn_cvt_f32_fp8(p01, 1);
    const float q2 = __builtin_amdgcn_cvt_f32_fp8(p23, 0);
    const float q3 = __builtin_amdgcn_cvt_f32_fp8(p23, 1);
    float sum = q0 * q0 + q1 * q1 + q2 * q2 + q3 * q3;
#pragma unroll
    for (int off = 32; off; off >>= 1) sum += __shfl_down(sum, off);
    if (lane == 0) xx[row] = sum;
}

// ---------- Kernel 2: fused MX-fp8 (K=128) distance-GEMM + arg-select -------
// R19: REGISTER DIET. Occupancy was pinned at ~24% (2 blocks/CU) in every
// round regardless of LDS or sync structure -> unified-file register demand
// (~210/wave: A_reg 64 + acc 32 + g_pk 16 + bestv 16 + bf 16 + addr) was the
// binder, capping 2 wave streams/SIMD; per-phase latency could not be hidden.
// Diet: g_pk -> LDS idxL[512]; acc[2][4] -> sequential-ct acc[4] (ct1 MFMAs
// overlap ct0 epilogue); blo/bhi/soff derived via XOR (bhi=blo^16, s1=^128,
// soff1=soff0^64). Target <=128/wave via __launch_bounds__(256,4).
// Pipeline: 4-buffer ring (32 KB), catalog-minimum 2-phase: issue tiles
// 2p+2,2p+3 at phase top (their slots were read in phase p-1; barrier just
// passed), vmcnt(0) with a full phase of cover. LDS 36 KB -> 4 blocks/CU.
// Keeps R16 MFMA-folded yy-2xy (A sign-flip fp8 + A-scale 2^1 + C=yv splat)
// and the XOR-swizzled staging (0 bank conflicts measured).
// enc=(bits(g)&~2047)|j merged via atomicMax/Min on monotone uint keys
// (2048-entry arrays; NEVER funnel same-address atomics: R18's single-cell
// atomicAdd cost +20 us).
// Grid 1280 = 8 i_blk x 4 jq x 40 (k,type); bid%40 -> same XCD per (k,type).
__global__ __launch_bounds__(256, 4) void select_k(
        const unsigned int* __restrict__ S8,
        const float* __restrict__ xx,
        const int* __restrict__ pos_idx,
        const int* __restrict__ neg_idx,
        unsigned int* __restrict__ hp,
        unsigned int* __restrict__ hn) {
    __shared__ __align__(16) unsigned char Bt[4][32 * 256];   // 32 KiB ring
    __shared__ float yyL[512];                                // 2 KiB
    __shared__ int   idxL[512];                               // 2 KiB

    const int tid    = threadIdx.x;
    const int w      = tid >> 6;        // 0..3 (i-quarter)
    const int lane   = tid & 63;
    const int lane15 = lane & 15;
    const int quad   = lane >> 4;

    const int bid    = blockIdx.x;      // 1280 = 32 (i_blk,jq) x 40 (k,type)
    const int ctid   = bid % 40;
    const int rest   = bid / 40;        // 0..31
    const int i_blk  = rest >> 2;       // 0..7
    const int jq     = rest & 3;        // 0..3
    const int k      = ctid >> 1;
    const int isNeg  = ctid & 1;
    const int i0     = i_blk * 256;
    const int j0     = jq * 512;        // 16 tiles of 32 j

    const int* __restrict__ idxA = pos_idx + k * P_POS;
    const int* __restrict__ idxB = (isNeg ? neg_idx : pos_idx) + k * P_POS;
    unsigned int* outKey         = (isNeg ? hn : hp) + k * P_POS;

    const char* S8B = (const char*)S8;          // row stride 256 B

    // ---- staging geometry (c=1 derived: rloc1=rloc0+4, soff1=soff0^64) ----
    const int rl    = lane >> 4;        // 0..3
    const int cch   = lane & 15;
    const int rloc0 = w * 8 + rl;                    // c=0 tile-local row
    const int soff0 = (cch ^ (rloc0 & 15)) << 4;     // c=0 swizzled src chunk

    // ---- idx + yy tables for this j-quarter (2 gathers/thread each) ----
#pragma unroll
    for (int t = 0; t < 2; ++t) {
        const int jj = t * 256 + tid;
        const int gj = idxB[j0 + jj];
        idxL[jj] = gj;
        yyL[jj]  = xx[gj];
    }

    // ---- A fragments: row i0+w*64+si*16+lane15, k0 = quad*32 + s*128 ----
    // Sign-flipped so that (with A-scale = 2^1) MFMA accumulates -2*x.y.
    Frag8 A_reg[4][2];
#pragma unroll
    for (int si = 0; si < 4; ++si) {
        const int gi = idxA[i0 + w * 64 + si * 16 + lane15];
        const char* rb = S8B + ((size_t)(uint32_t)gi << 8) + quad * 32;
#pragma unroll
        for (int s = 0; s < 2; ++s) {
            A_reg[si][s].q[0] = *(const uint4*)(rb + s * 128);
            A_reg[si][s].q[1] = *(const uint4*)(rb + s * 128 + 16);
            negA(A_reg[si][s]);
        }
    }

    // ---- LDS read base: s=0 lo chunk c0=quad*2; derive ^16 (hi), ^128 (s=1)
    const int blo0 = lane15 * 256 + (((quad * 2) ^ lane15) << 4);

    float bestv[16];
    const float binit = isNeg ? 3.4e38f : -3.4e38f;
#pragma unroll
    for (int t = 0; t < 16; ++t) bestv[t] = binit;

    // ---- drain ALL prologue VMEM + publish idxL/yyL; after this the only
    //      outstanding VMEM is async copies -> exact vmcnt counting.
    __syncthreads();

    // ---- prologue: issue tiles 0..3 (8 copies/wave) ----
#pragma unroll
    for (int t = 0; t < 4; ++t) {
        const int b  = (t << 5) + rloc0;
        const int r0 = idxL[b];
        const int r1 = idxL[b + 4];
        char* lb = (char*)&Bt[t][0] + (w * 2) * 1024;
        async_copy16(S8B + ((size_t)(uint32_t)r0 << 8) + soff0,        lb);
        async_copy16(S8B + ((size_t)(uint32_t)r1 << 8) + (soff0 ^ 64), lb + 1024);
    }

#pragma unroll
    for (int p = 0; p < 8; ++p) {
        // need tiles 2p,2p+1 landed (issued >=1 phase ago). p=0: leave
        // tiles 2,3 in flight; p>=1: everything outstanding is exactly the
        // tiles needed next -> counted drain with a full phase of cover.
        if (p == 0) { asm volatile("s_waitcnt vmcnt(4)" ::: "memory"); }
        else        { asm volatile("s_waitcnt vmcnt(0)" ::: "memory"); }
        __builtin_amdgcn_s_barrier();
        __builtin_amdgcn_sched_barrier(0);

        // issue tiles 2p+2,2p+3 into the slots read in phase p-1 (all waves
        // done reading them: the barrier above). Used at top of phase p+1.
        if (p >= 1 && p <= 6) {
            const int t = 2 * p + 2;
#pragma unroll
            for (int u = 0; u < 2; ++u) {
                const int b  = ((t + u) << 5) + rloc0;
                const int r0 = idxL[b];
                const int r1 = idxL[b + 4];
                char* lb = (char*)&Bt[(t + u) & 3][0] + (w * 2) * 1024;
                async_copy16(S8B + ((size_t)(uint32_t)r0 << 8) + soff0,        lb);
                async_copy16(S8B + ((size_t)(uint32_t)r1 << 8) + (soff0 ^ 64), lb + 1024);
            }
        }

        // ---- compute tiles 2p, 2p+1; sequential ct reuses acc[4] (16 regs);
        //      first K-step carries yy in C -> acc = yy - 2xy.
#pragma unroll
        for (int u = 0; u < 2; ++u) {
            const int jc = 2 * p + u;
            const char* Bb = (const char*)&Bt[jc & 3][0];
#pragma unroll
            for (int ct = 0; ct < 2; ++ct) {
                const float yv = yyL[(jc << 5) + (ct << 4) + lane15];
                const floatx4 yv4 = {yv, yv, yv, yv};
                const int cto = ct << 12;
                Frag8 bf;
                bf.q[0] = *(const uint4*)(Bb + (blo0      ) + cto);
                bf.q[1] = *(const uint4*)(Bb + (blo0 ^ 16 ) + cto);
                floatx4 acc[4];
#pragma unroll
                for (int si = 0; si < 4; ++si)
                    acc[si] = __builtin_amdgcn_mfma_scale_f32_16x16x128_f8f6f4(
                        A_reg[si][0].v, bf.v, yv4, 0, 0,
                        0, SCALE2, 0, SCALE1);
                bf.q[0] = *(const uint4*)(Bb + (blo0 ^ 128) + cto);
                bf.q[1] = *(const uint4*)(Bb + (blo0 ^ 144) + cto);
#pragma unroll
                for (int si = 0; si < 4; ++si)
                    acc[si] = __builtin_amdgcn_mfma_scale_f32_16x16x128_f8f6f4(
                        A_reg[si][1].v, bf.v, acc[si], 0, 0,
                        0, SCALE2, 0, SCALE1);

                // epilogue: acc already = yy-2xy. enc = (bits&~2047)|j
                const uint32_t jb =
                    (uint32_t)((j0 + (jc << 5) + (ct << 4)) | lane15);
#pragma unroll
                for (int si = 0; si < 4; ++si)
#pragma unroll
                    for (int r = 0; r < 4; ++r) {
                        const float e = __uint_as_float(
                            (__float_as_uint(acc[si][r]) & 0xFFFFF800u) | jb);
                        const int slot = si * 4 + r;
                        bestv[slot] = isNeg ? fminf(bestv[slot], e)
                                            : fmaxf(bestv[slot], e);
                    }
            }
        }
    }

    // ---- reduce over the 16 column-lanes (index rides in the bits) ----
#pragma unroll
    for (int slot = 0; slot < 16; ++slot) {
#pragma unroll
        for (int off = 1; off < 16; off <<= 1) {
            const float ov = __shfl_xor(bestv[slot], off);
            bestv[slot] = isNeg ? fminf(bestv[slot], ov) : fmaxf(bestv[slot], ov);
        }
    }
    // ---- merge across j-quarters: monotone-mapped key + device atomics ----
    if (lane15 == 0) {
#pragma unroll
        for (int si = 0; si < 4; ++si)
#pragma unroll
            for (int r = 0; r < 4; ++r) {
                const int row = w * 64 + si * 16 + quad * 4 + r;
                const uint32_t u = __float_as_uint(bestv[si * 4 + r]);
                const uint32_t key = (u & 0x80000000u) ? ~u : (u | 0x80000000u);
                if (isNeg) atomicMin(&outKey[i0 + row], key);
                else       atomicMax(&outKey[i0 + row], key);
            }
    }
}

// ------- Kernel 3: per-anchor pdist from fp8 table (16 lanes/anchor) --------
#define ACC16(UA, UP, UN)                                                     \
    {                                                                         \
        float xa, d;                                                          \
        xa = __builtin_amdgcn_cvt_f32_fp8((int)(UA), 0);                      \
        d = xa - __builtin_amdgcn_cvt_f32_fp8((int)(UP), 0); dp += d * d;     \
        d = xa - __builtin_amdgcn_cvt_f32_fp8((int)(UN), 0); dn += d * d;     \
        xa = __builtin_amdgcn_cvt_f32_fp8((int)(UA), 1);                      \
        d = xa - __builtin_amdgcn_cvt_f32_fp8((int)(UP), 1); dp += d * d;     \
        d = xa - __builtin_amdgcn_cvt_f32_fp8((int)(UN), 1); dn += d * d;     \
        xa = __builtin_amdgcn_cvt_f32_fp8((int)(UA), 2);                      \
        d = xa - __builtin_amdgcn_cvt_f32_fp8((int)(UP), 2); dp += d * d;     \
        d = xa - __builtin_amdgcn_cvt_f32_fp8((int)(UN), 2); dn += d * d;     \
        xa = __builtin_amdgcn_cvt_f32_fp8((int)(UA), 3);                      \
        d = xa - __builtin_amdgcn_cvt_f32_fp8((int)(UP), 3); dp += d * d;     \
        d = xa - __builtin_amdgcn_cvt_f32_fp8((int)(UN), 3); dn += d * d;     \
    }

__global__ __launch_bounds__(256) void loss_k(
        const unsigned int* __restrict__ S8,
        const int* __restrict__ pos_idx,
        const int* __restrict__ neg_idx,
        const unsigned int* __restrict__ hp,
        const unsigned int* __restrict__ hn,
        float* __restrict__ terms) {
    const int tid    = threadIdx.x;
    const int lane15 = tid & 15;
    const int grp    = tid >> 4;               // 0..15: anchor group in block
    const int a      = blockIdx.x * 16 + grp;  // 2048%16==0 -> one class/block
    const int k      = a >> 11;
    const int i      = a & 2047;
    const int* pidx = pos_idx + (k << 11);
    const int* nidx = neg_idx + (k << 11);
    const unsigned int kp = hp[a], kn = hn[a];
    const int jp = (int)((kp & 0x80000000u) ? (kp & 2047u) : ((~kp) & 2047u));
    const int jn = (int)((kn & 0x80000000u) ? (kn & 2047u) : ((~kn) & 2047u));
    const int ga = pidx[i];
    const int gp = pidx[jp];
    const int gn = nidx[jn];

    const char* S8B = (const char*)S8;
    const uint4 va = *(const uint4*)(S8B + ((size_t)(uint32_t)ga << 8) + lane15 * 16);
    const uint4 vp = *(const uint4*)(S8B + ((size_t)(uint32_t)gp << 8) + lane15 * 16);
    const uint4 vn = *(const uint4*)(S8B + ((size_t)(uint32_t)gn << 8) + lane15 * 16);

    float dp = 0.f, dn = 0.f;
    ACC16(va.x, vp.x, vn.x)
    ACC16(va.y, vp.y, vn.y)
    ACC16(va.z, vp.z, vn.z)
    ACC16(va.w, vp.w, vn.w)

#pragma unroll
    for (int off = 1; off < 16; off <<= 1) {   // xor stays within 16-lane group
        dp += __shfl_xor(dp, off);
        dn += __shfl_xor(dn, off);
    }
    if (lane15 == 0) {
        const float d_p = sqrtf(fmaxf(dp, 0.f) + EPS_D);
        const float d_n = sqrtf(fmaxf(dn, 0.f) + EPS_D);
        terms[a] = fmaxf(MARGIN_F + d_p - d_n, 0.f);
    }
}

// ---------------- Kernel 4: final reduction (sum of class means) ------------
__global__ __launch_bounds__(1024) void reduce_k(
        const float* __restrict__ terms, float* __restrict__ out) {
    __shared__ float red[1024];
    float s = 0.f;
    for (int i = threadIdx.x; i < K_CLS * P_POS; i += 1024) s += terms[i];
    red[threadIdx.x] = s;
    __syncthreads();
    for (int off = 512; off; off >>= 1) {
        if ((int)threadIdx.x < off) red[threadIdx.x] += red[threadIdx.x + off];
        __syncthreads();
    }
    if (threadIdx.x == 0) out[0] = red[0] * (1.0f / (float)P_POS);
}

extern "C" void kernel_launch(void* const* d_in, const int* in_sizes, int n_in,
                              void* d_out, int out_size, void* d_ws, size_t ws_size,
                              hipStream_t stream) {
    const float* feat    = (const float*)d_in[0];
    const int*   pos_idx = (const int*)d_in[1];
    const int*   neg_idx = (const int*)d_in[2];

    char* ws = (char*)d_ws;
    unsigned int* S8 = (unsigned int*)ws;                     // 16 MiB fp8 table
    float*        xx = (float*)(ws + 16777216);               // 256 KiB norms
    unsigned int* hp = (unsigned int*)(ws + 17039360);        // 160 KiB keys
    unsigned int* hn = (unsigned int*)(ws + 17203200);        // 160 KiB keys
    float*     terms = (float*)(ws + 17367040);               // 160 KiB

    sigmoid_norm_k<<<M_ROWS / 4, 256, 0, stream>>>(feat, S8, xx, hp, hn);

    select_k<<<32 * 40, 256, 0, stream>>>(S8, xx, pos_idx, neg_idx, hp, hn);

    loss_k<<<(K_CLS * P_POS) / 16, 256, 0, stream>>>(S8, pos_idx, neg_idx, hp, hn, terms);

    reduce_k<<<1, 1024, 0, stream>>>(terms, (float*)d_out);
}

// Round 5
// 164.598 us; speedup vs baseline: 1.4829x; 1.4829x over previous
//
#include <hip/hip_runtime.h>
#include <stdint.h>

#define M_ROWS 65536
#define C_DIM  256
#define K_CLS  20
#define P_POS  2048
#define MARGIN_F 0.3f
#define EPS_D (0.0001f / 256.0f)
#define SCALE1 0x7F7F7F7Fu   /* e8m0 127 = 2^0 in all four bytes */
#define SCALE2 0x80808080u   /* e8m0 128 = 2^1 in all four bytes (A operand) */

typedef float floatx4 __attribute__((ext_vector_type(4)));
typedef int   intx8   __attribute__((ext_vector_type(8)));
union Frag8 { intx8 v; uint4 q[2]; };

// async 16B/lane global -> LDS (wave-uniform LDS base + lane*16)
__device__ __forceinline__ void async_copy16(const void* g, void* l) {
    __builtin_amdgcn_global_load_lds(
        (const __attribute__((address_space(1))) void*)g,
        (__attribute__((address_space(3))) void*)l, 16, 0, 0);
}
__device__ __forceinline__ float sigm(float x) { return 1.f / (1.f + __expf(-x)); }

// flip fp8 e4m3 signs (sign-magnitude; sigmoid outputs have no NaN/Inf)
__device__ __forceinline__ void negA(Frag8& f) {
#pragma unroll
    for (int t = 0; t < 8; ++t) f.v[t] ^= (int)0x80808080u;
}

// ------- Kernel 1: sigmoid -> fp8 e4m3 table + fp8-exact row norms ----------
__global__ __launch_bounds__(256) void sigmoid_norm_k(
        const float* __restrict__ feat,
        unsigned int* __restrict__ S8,     // [M][64] uint = 256 fp8/row
        float* __restrict__ xx,
        unsigned int* __restrict__ hp,
        unsigned int* __restrict__ hn,
        float* __restrict__ out) {
    {
        const int idx = blockIdx.x * 256 + threadIdx.x;
        if (idx < K_CLS * P_POS) { hp[idx] = 0u; hn[idx] = 0xFFFFFFFFu; }
        if (idx == 0) out[0] = 0.f;   // loss accumulator (reduce_k atomicAdds)
    }
    const int wave = threadIdx.x >> 6, lane = threadIdx.x & 63;
    const int row = blockIdx.x * 4 + wave;
    const float4 v = *(const float4*)(feat + (size_t)row * C_DIM + lane * 4);

    const int p01 = __builtin_amdgcn_cvt_pk_fp8_f32(sigm(v.x), sigm(v.y), 0, false);
    const int p23 = __builtin_amdgcn_cvt_pk_fp8_f32(sigm(v.z), sigm(v.w), 0, false);
    const unsigned int packed = (unsigned int)(p01 & 0xFFFF) | ((unsigned int)p23 << 16);
    S8[(size_t)row * 64 + lane] = packed;

    const float q0 = __builtin_amdgcn_cvt_f32_fp8(p01, 0);
    const float q1 = __builtin_amdgcn_cvt_f32_fp8(p01, 1);
    const float q2 = __builtin_amdgcn_cvt_f32_fp8(p23, 0);
    const float q3 = __builtin_amdgcn_cvt_f32_fp8(p23, 1);
    float sum = q0 * q0 + q1 * q1 + q2 * q2 + q3 * q3;
#pragma unroll
    for (int off = 32; off; off >>= 1) sum += __shfl_down(sum, off);
    if (lane == 0) xx[row] = sum;
}

// ---------- Kernel 2: fused MX-fp8 (K=128) distance-GEMM + arg-select -------
// R20: HALVED WAVE TILE for occupancy. Post-mortem history:
//   * R2/R3/R18: three sync structures all ~62 us, occupancy pinned 24%
//     (2 waves/SIMD) -> latency per phase unhidden.
//   * R19: forcing 4 waves via launch_bounds(256,4) SPILLED (FETCH 21->238 MB,
//     WRITE 12->112 MB, 2.5 TB/s of scratch traffic): true unified VGPR+AGPR
//     demand ~200+/wave (rocprof VGPR_Count=84 excludes AGPRs).
// Fix: shrink algorithmic state. Wave tile 64x32 -> 32x32: A_reg 32, acc 8,
// bestv 8; block = 128 i-rows; grid 2560 (16 i_blk x 4 jq x 40) -> ~10
// blocks/CU queued. Target 3 waves/SIMD WITHOUT forcing (launch_bounds(256,3),
// proven spill-free). B-staging traffic doubles (L3-served, cheap).
// Pipeline (R19's, correctness-proven): 4-buffer ring (32 KB), issue tiles
// 2p+2,2p+3 at phase top (their slots were read in phase p-1), counted
// vmcnt with a full phase of cover. idxL/yyL in LDS.
// Keeps R16 MFMA-folded yy-2xy (A sign-flip fp8 + A-scale 2^1 + C=yv splat)
// and XOR-swizzled staging (0 bank conflicts measured).
// enc=(bits(g)&~2047)|j merged via atomicMax/Min on monotone uint keys
// (2048-entry arrays; NEVER funnel same-address atomics: R18 cost +20 us).
__global__ __launch_bounds__(256, 3) void select_k(
        const unsigned int* __restrict__ S8,
        const float* __restrict__ xx,
        const int* __restrict__ pos_idx,
        const int* __restrict__ neg_idx,
        unsigned int* __restrict__ hp,
        unsigned int* __restrict__ hn) {
    __shared__ __align__(16) unsigned char Bt[4][32 * 256];   // 32 KiB ring
    __shared__ float yyL[512];                                // 2 KiB
    __shared__ int   idxL[512];                               // 2 KiB

    const int tid    = threadIdx.x;
    const int w      = tid >> 6;        // 0..3 (i-eighth of 128-row block)
    const int lane   = tid & 63;
    const int lane15 = lane & 15;
    const int quad   = lane >> 4;

    const int bid    = blockIdx.x;      // 2560 = 64 (i_blk,jq) x 40 (k,type)
    const int ctid   = bid % 40;
    const int rest   = bid / 40;        // 0..63
    const int i_blk  = rest >> 2;       // 0..15
    const int jq     = rest & 3;        // 0..3
    const int k      = ctid >> 1;
    const int isNeg  = ctid & 1;
    const int i0     = i_blk * 128;
    const int j0     = jq * 512;        // 16 tiles of 32 j

    const int* __restrict__ idxA = pos_idx + k * P_POS;
    const int* __restrict__ idxB = (isNeg ? neg_idx : pos_idx) + k * P_POS;
    unsigned int* outKey         = (isNeg ? hn : hp) + k * P_POS;

    const char* S8B = (const char*)S8;          // row stride 256 B

    // ---- staging geometry (c=1 derived: rloc1=rloc0+4, soff1=soff0^64) ----
    const int rl    = lane >> 4;        // 0..3
    const int cch   = lane & 15;
    const int rloc0 = w * 8 + rl;                    // c=0 tile-local row
    const int soff0 = (cch ^ (rloc0 & 15)) << 4;     // c=0 swizzled src chunk

    // ---- idx + yy tables for this j-quarter (2 gathers/thread each) ----
#pragma unroll
    for (int t = 0; t < 2; ++t) {
        const int jj = t * 256 + tid;
        const int gj = idxB[j0 + jj];
        idxL[jj] = gj;
        yyL[jj]  = xx[gj];
    }

    // ---- A fragments: row i0+w*32+si*16+lane15, k0 = quad*32 + s*128 ----
    // Sign-flipped so that (with A-scale = 2^1) MFMA accumulates -2*x.y.
    Frag8 A_reg[2][2];
#pragma unroll
    for (int si = 0; si < 2; ++si) {
        const int gi = idxA[i0 + w * 32 + si * 16 + lane15];
        const char* rb = S8B + ((size_t)(uint32_t)gi << 8) + quad * 32;
#pragma unroll
        for (int s = 0; s < 2; ++s) {
            A_reg[si][s].q[0] = *(const uint4*)(rb + s * 128);
            A_reg[si][s].q[1] = *(const uint4*)(rb + s * 128 + 16);
            negA(A_reg[si][s]);
        }
    }

    // ---- LDS read base: s=0 lo chunk c0=quad*2; derive ^16 (hi), ^128 (s=1)
    const int blo0 = lane15 * 256 + (((quad * 2) ^ lane15) << 4);

    float bestv[8];
    const float binit = isNeg ? 3.4e38f : -3.4e38f;
#pragma unroll
    for (int t = 0; t < 8; ++t) bestv[t] = binit;

    // ---- drain ALL prologue VMEM + publish idxL/yyL; after this the only
    //      outstanding VMEM is async copies -> exact vmcnt counting.
    __syncthreads();

    // ---- prologue: issue tiles 0..3 (8 copies/wave) ----
#pragma unroll
    for (int t = 0; t < 4; ++t) {
        const int b  = (t << 5) + rloc0;
        const int r0 = idxL[b];
        const int r1 = idxL[b + 4];
        char* lb = (char*)&Bt[t][0] + (w * 2) * 1024;
        async_copy16(S8B + ((size_t)(uint32_t)r0 << 8) + soff0,        lb);
        async_copy16(S8B + ((size_t)(uint32_t)r1 << 8) + (soff0 ^ 64), lb + 1024);
    }

#pragma unroll
    for (int p = 0; p < 8; ++p) {
        // need tiles 2p,2p+1 landed. p=0: leave tiles 2,3 in flight (vmcnt 4);
        // p>=1: everything outstanding was issued one full phase ago ->
        // counted drain with a phase of latency cover.
        if (p == 0) { asm volatile("s_waitcnt vmcnt(4)" ::: "memory"); }
        else        { asm volatile("s_waitcnt vmcnt(0)" ::: "memory"); }
        __builtin_amdgcn_s_barrier();
        __builtin_amdgcn_sched_barrier(0);

        // issue tiles 2p+2,2p+3 into the slots read in phase p-1 (all waves
        // done reading them: the barrier above). Used at top of phase p+1.
        if (p >= 1 && p <= 6) {
            const int t = 2 * p + 2;
#pragma unroll
            for (int u = 0; u < 2; ++u) {
                const int b  = ((t + u) << 5) + rloc0;
                const int r0 = idxL[b];
                const int r1 = idxL[b + 4];
                char* lb = (char*)&Bt[(t + u) & 3][0] + (w * 2) * 1024;
                async_copy16(S8B + ((size_t)(uint32_t)r0 << 8) + soff0,        lb);
                async_copy16(S8B + ((size_t)(uint32_t)r1 << 8) + (soff0 ^ 64), lb + 1024);
            }
        }

        // ---- compute tiles 2p, 2p+1; sequential ct reuses acc[2] (8 regs);
        //      first K-step carries yy in C -> acc = yy - 2xy.
#pragma unroll
        for (int u = 0; u < 2; ++u) {
            const int jc = 2 * p + u;
            const char* Bb = (const char*)&Bt[jc & 3][0];
#pragma unroll
            for (int ct = 0; ct < 2; ++ct) {
                const float yv = yyL[(jc << 5) + (ct << 4) + lane15];
                const floatx4 yv4 = {yv, yv, yv, yv};
                const int cto = ct << 12;
                Frag8 bf;
                bf.q[0] = *(const uint4*)(Bb + (blo0      ) + cto);
                bf.q[1] = *(const uint4*)(Bb + (blo0 ^ 16 ) + cto);
                floatx4 acc[2];
#pragma unroll
                for (int si = 0; si < 2; ++si)
                    acc[si] = __builtin_amdgcn_mfma_scale_f32_16x16x128_f8f6f4(
                        A_reg[si][0].v, bf.v, yv4, 0, 0,
                        0, SCALE2, 0, SCALE1);
                bf.q[0] = *(const uint4*)(Bb + (blo0 ^ 128) + cto);
                bf.q[1] = *(const uint4*)(Bb + (blo0 ^ 144) + cto);
#pragma unroll
                for (int si = 0; si < 2; ++si)
                    acc[si] = __builtin_amdgcn_mfma_scale_f32_16x16x128_f8f6f4(
                        A_reg[si][1].v, bf.v, acc[si], 0, 0,
                        0, SCALE2, 0, SCALE1);

                // epilogue: acc already = yy-2xy. enc = (bits&~2047)|j
                const uint32_t jb =
                    (uint32_t)((j0 + (jc << 5) + (ct << 4)) | lane15);
#pragma unroll
                for (int si = 0; si < 2; ++si)
#pragma unroll
                    for (int r = 0; r < 4; ++r) {
                        const float e = __uint_as_float(
                            (__float_as_uint(acc[si][r]) & 0xFFFFF800u) | jb);
                        const int slot = si * 4 + r;
                        bestv[slot] = isNeg ? fminf(bestv[slot], e)
                                            : fmaxf(bestv[slot], e);
                    }
            }
        }
    }

    // ---- reduce over the 16 column-lanes (index rides in the bits) ----
#pragma unroll
    for (int slot = 0; slot < 8; ++slot) {
#pragma unroll
        for (int off = 1; off < 16; off <<= 1) {
            const float ov = __shfl_xor(bestv[slot], off);
            bestv[slot] = isNeg ? fminf(bestv[slot], ov) : fmaxf(bestv[slot], ov);
        }
    }
    // ---- merge across j-quarters: monotone-mapped key + device atomics ----
    if (lane15 == 0) {
#pragma unroll
        for (int si = 0; si < 2; ++si)
#pragma unroll
            for (int r = 0; r < 4; ++r) {
                const int row = w * 32 + si * 16 + quad * 4 + r;
                const uint32_t u = __float_as_uint(bestv[si * 4 + r]);
                const uint32_t key = (u & 0x80000000u) ? ~u : (u | 0x80000000u);
                if (isNeg) atomicMin(&outKey[i0 + row], key);
                else       atomicMax(&outKey[i0 + row], key);
            }
    }
}

// ------- Kernel 3: per-anchor pdist from fp8 table (16 lanes/anchor) --------
#define ACC16(UA, UP, UN)                                                     \
    {                                                                         \
        float xa, d;                                                          \
        xa = __builtin_amdgcn_cvt_f32_fp8((int)(UA), 0);                      \
        d = xa - __builtin_amdgcn_cvt_f32_fp8((int)(UP), 0); dp += d * d;     \
        d = xa - __builtin_amdgcn_cvt_f32_fp8((int)(UN), 0); dn += d * d;     \
        xa = __builtin_amdgcn_cvt_f32_fp8((int)(UA), 1);                      \
        d = xa - __builtin_amdgcn_cvt_f32_fp8((int)(UP), 1); dp += d * d;     \
        d = xa - __builtin_amdgcn_cvt_f32_fp8((int)(UN), 1); dn += d * d;     \
        xa = __builtin_amdgcn_cvt_f32_fp8((int)(UA), 2);                      \
        d = xa - __builtin_amdgcn_cvt_f32_fp8((int)(UP), 2); dp += d * d;     \
        d = xa - __builtin_amdgcn_cvt_f32_fp8((int)(UN), 2); dn += d * d;     \
        xa = __builtin_amdgcn_cvt_f32_fp8((int)(UA), 3);                      \
        d = xa - __builtin_amdgcn_cvt_f32_fp8((int)(UP), 3); dp += d * d;     \
        d = xa - __builtin_amdgcn_cvt_f32_fp8((int)(UN), 3); dn += d * d;     \
    }

__global__ __launch_bounds__(256) void loss_k(
        const unsigned int* __restrict__ S8,
        const int* __restrict__ pos_idx,
        const int* __restrict__ neg_idx,
        const unsigned int* __restrict__ hp,
        const unsigned int* __restrict__ hn,
        float* __restrict__ terms) {
    const int tid    = threadIdx.x;
    const int lane15 = tid & 15;
    const int grp    = tid >> 4;               // 0..15: anchor group in block
    const int a      = blockIdx.x * 16 + grp;  // 2048%16==0 -> one class/block
    const int k      = a >> 11;
    const int i      = a & 2047;
    const int* pidx = pos_idx + (k << 11);
    const int* nidx = neg_idx + (k << 11);
    const unsigned int kp = hp[a], kn = hn[a];
    const int jp = (int)((kp & 0x80000000u) ? (kp & 2047u) : ((~kp) & 2047u));
    const int jn = (int)((kn & 0x80000000u) ? (kn & 2047u) : ((~kn) & 2047u));
    const int ga = pidx[i];
    const int gp = pidx[jp];
    const int gn = nidx[jn];

    const char* S8B = (const char*)S8;
    const uint4 va = *(const uint4*)(S8B + ((size_t)(uint32_t)ga << 8) + lane15 * 16);
    const uint4 vp = *(const uint4*)(S8B + ((size_t)(uint32_t)gp << 8) + lane15 * 16);
    const uint4 vn = *(const uint4*)(S8B + ((size_t)(uint32_t)gn << 8) + lane15 * 16);

    float dp = 0.f, dn = 0.f;
    ACC16(va.x, vp.x, vn.x)
    ACC16(va.y, vp.y, vn.y)
    ACC16(va.z, vp.z, vn.z)
    ACC16(va.w, vp.w, vn.w)

#pragma unroll
    for (int off = 1; off < 16; off <<= 1) {   // xor stays within 16-lane group
        dp += __shfl_xor(dp, off);
        dn += __shfl_xor(dn, off);
    }
    if (lane15 == 0) {
        const float d_p = sqrtf(fmaxf(dp, 0.f) + EPS_D);
        const float d_n = sqrtf(fmaxf(dn, 0.f) + EPS_D);
        terms[a] = fmaxf(MARGIN_F + d_p - d_n, 0.f);
    }
}

// ---------------- Kernel 4: final reduction (sum of class means) ------------
// R20: 40 blocks (was 1 -> serialized tail). One atomicAdd per block (40
// same-line atomics ~0.3 us, unlike R18's 2560 which cost +20 us).
__global__ __launch_bounds__(1024) void reduce_k(
        const float* __restrict__ terms, float* __restrict__ out) {
    __shared__ float red[1024];
    const int tid = threadIdx.x;
    red[tid] = terms[blockIdx.x * 1024 + tid];   // 40*1024 == 40960 exactly
    __syncthreads();
    for (int off = 512; off; off >>= 1) {
        if (tid < off) red[tid] += red[tid + off];
        __syncthreads();
    }
    if (tid == 0) atomicAdd(out, red[0] * (1.0f / (float)P_POS));
}

extern "C" void kernel_launch(void* const* d_in, const int* in_sizes, int n_in,
                              void* d_out, int out_size, void* d_ws, size_t ws_size,
                              hipStream_t stream) {
    const float* feat    = (const float*)d_in[0];
    const int*   pos_idx = (const int*)d_in[1];
    const int*   neg_idx = (const int*)d_in[2];

    char* ws = (char*)d_ws;
    unsigned int* S8 = (unsigned int*)ws;                     // 16 MiB fp8 table
    float*        xx = (float*)(ws + 16777216);               // 256 KiB norms
    unsigned int* hp = (unsigned int*)(ws + 17039360);        // 160 KiB keys
    unsigned int* hn = (unsigned int*)(ws + 17203200);        // 160 KiB keys
    float*     terms = (float*)(ws + 17367040);               // 160 KiB

    sigmoid_norm_k<<<M_ROWS / 4, 256, 0, stream>>>(feat, S8, xx, hp, hn,
                                                   (float*)d_out);

    select_k<<<64 * 40, 256, 0, stream>>>(S8, xx, pos_idx, neg_idx, hp, hn);

    loss_k<<<(K_CLS * P_POS) / 16, 256, 0, stream>>>(S8, pos_idx, neg_idx, hp, hn, terms);

    reduce_k<<<40, 1024, 0, stream>>>(terms, (float*)d_out);
}

// Round 6
// 161.821 us; speedup vs baseline: 1.5084x; 1.0172x over previous
//
#include <hip/hip_runtime.h>
#include <stdint.h>

#define M_ROWS 65536
#define C_DIM  256
#define K_CLS  20
#define P_POS  2048
#define MARGIN_F 0.3f
#define EPS_D (0.0001f / 256.0f)
#define SCALE1 0x7F7F7F7Fu   /* e8m0 127 = 2^0 in all four bytes */
#define SCALE2 0x80808080u   /* e8m0 128 = 2^1 in all four bytes (A operand) */

typedef float floatx4 __attribute__((ext_vector_type(4)));
typedef int   intx8   __attribute__((ext_vector_type(8)));
union Frag8 { intx8 v; uint4 q[2]; };

// async 16B/lane global -> LDS (wave-uniform LDS base + lane*16)
__device__ __forceinline__ void async_copy16(const void* g, void* l) {
    __builtin_amdgcn_global_load_lds(
        (const __attribute__((address_space(1))) void*)g,
        (__attribute__((address_space(3))) void*)l, 16, 0, 0);
}
__device__ __forceinline__ float sigm(float x) { return 1.f / (1.f + __expf(-x)); }

// flip fp8 e4m3 signs (sign-magnitude; sigmoid outputs have no NaN/Inf)
__device__ __forceinline__ void negA(Frag8& f) {
#pragma unroll
    for (int t = 0; t < 8; ++t) f.v[t] ^= (int)0x80808080u;
}

#define VMCNT2() asm volatile("s_waitcnt vmcnt(2)" ::: "memory")
#define VMCNT0() asm volatile("s_waitcnt vmcnt(0)" ::: "memory")

// ------- Kernel 1: sigmoid -> fp8 e4m3 table + fp8-exact row norms ----------
__global__ __launch_bounds__(256) void sigmoid_norm_k(
        const float* __restrict__ feat,
        unsigned int* __restrict__ S8,     // [M][64] uint = 256 fp8/row
        float* __restrict__ xx,
        unsigned int* __restrict__ hp,
        unsigned int* __restrict__ hn,
        float* __restrict__ out) {
    {
        const int idx = blockIdx.x * 256 + threadIdx.x;
        if (idx < K_CLS * P_POS) { hp[idx] = 0u; hn[idx] = 0xFFFFFFFFu; }
        if (idx == 0) out[0] = 0.f;   // loss accumulator (reduce_k atomicAdds)
    }
    const int wave = threadIdx.x >> 6, lane = threadIdx.x & 63;
    const int row = blockIdx.x * 4 + wave;
    const float4 v = *(const float4*)(feat + (size_t)row * C_DIM + lane * 4);

    const int p01 = __builtin_amdgcn_cvt_pk_fp8_f32(sigm(v.x), sigm(v.y), 0, false);
    const int p23 = __builtin_amdgcn_cvt_pk_fp8_f32(sigm(v.z), sigm(v.w), 0, false);
    const unsigned int packed = (unsigned int)(p01 & 0xFFFF) | ((unsigned int)p23 << 16);
    S8[(size_t)row * 64 + lane] = packed;

    const float q0 = __builtin_amdgcn_cvt_f32_fp8(p01, 0);
    const float q1 = __builtin_amdgcn_cvt_f32_fp8(p01, 1);
    const float q2 = __builtin_amdgcn_cvt_f32_fp8(p23, 0);
    const float q3 = __builtin_amdgcn_cvt_f32_fp8(p23, 1);
    float sum = q0 * q0 + q1 * q1 + q2 * q2 + q3 * q3;
#pragma unroll
    for (int off = 32; off; off >>= 1) sum += __shfl_down(sum, off);
    if (lane == 0) xx[row] = sum;
}

// ---------- Kernel 2: fused MX-fp8 (K=128) distance-GEMM + arg-select -------
// R21: EXPLICIT-LDS B reads. All prior rounds read the B tile via
// (char*)&Bt[jc%3][0] + byte-offset casts. If InferAddressSpaces fails on
// that pattern, the reads are flat_load_dwordx4: they increment vmcnt, so
// the compiler must drain vmcnt before every MFMA B-use -> the async
// global_load_lds prefetch queue is drained EVERY TILE, which exactly
// matches the observed invariants (3 sync structures all ~62-74 us, MfmaUtil
// pinned 22-26%, pipelining nulls, SQ_LDS_BANK_CONFLICT == 0 everywhere).
// Fix: typed __shared__ uint4 Bt4[3][512], direct array indexing with
// compile-time buffer index (loop fully unrolled) -> guaranteed ds_read_b128.
// XOR swizzle in uint4-index space: lo=bidx0, hi=^1, s=1 -> ^8/^9, ct=1 ->
// +256. Geometry = R17 (best measured): 64x32 wave tile, 1280 blocks,
// triple-buffer ring, g_pk reg-preloaded indices, vmcnt(2)-counted waits.
// Keeps R16 MFMA-folded yy-2xy (A sign-flip fp8 + A-scale 2^1 + C=yv splat).
// enc=(bits(g)&~2047)|j merged via atomicMax/Min on monotone uint keys
// (2048-entry arrays; NEVER funnel same-address atomics: R18 cost +20 us).
// Grid 1280 = 8 i_blk x 4 jq x 40 (k,type); bid%40 -> same XCD per (k,type).
__global__ __launch_bounds__(256, 3) void select_k(
        const unsigned int* __restrict__ S8,
        const float* __restrict__ xx,
        const int* __restrict__ pos_idx,
        const int* __restrict__ neg_idx,
        unsigned int* __restrict__ hp,
        unsigned int* __restrict__ hn) {
    __shared__ __align__(16) uint4 Bt4[3][512];   // 3 x 8 KiB ring
    __shared__ float yyL[512];                    // 2 KiB

    const int tid    = threadIdx.x;
    const int w      = tid >> 6;        // 0..3 (i-quarter)
    const int lane   = tid & 63;
    const int lane15 = lane & 15;
    const int quad   = lane >> 4;

    const int bid    = blockIdx.x;      // 1280 = 32 (i_blk,jq) x 40 (k,type)
    const int ctid   = bid % 40;
    const int rest   = bid / 40;        // 0..31
    const int i_blk  = rest >> 2;       // 0..7
    const int jq     = rest & 3;        // 0..3
    const int k      = ctid >> 1;
    const int isNeg  = ctid & 1;
    const int i0     = i_blk * 256;
    const int j0     = jq * 512;        // 16 tiles of 32 j

    const int* __restrict__ idxA = pos_idx + k * P_POS;
    const int* __restrict__ idxB = (isNeg ? neg_idx : pos_idx) + k * P_POS;
    unsigned int* outKey         = (isNeg ? hn : hp) + k * P_POS;

    const char* S8B = (const char*)S8;          // row stride 256 B

    // ---- staging geometry: 8 ops/tile (2 per wave), 4 rows per op ----
    const int rl  = lane >> 4;          // 0..3
    const int cch = lane & 15;
    int rloc[2], soff[2];
#pragma unroll
    for (int c = 0; c < 2; ++c) {
        rloc[c] = (w * 2 + c) * 4 + rl;                  // tile-local row
        soff[c] = (cch ^ (rloc[c] & 15)) << 4;           // swizzled source chunk
    }

    // ---- preload ALL staging row indices (rows < 65536 -> 2x16-bit pack) ---
    uint32_t g_pk[16];
#pragma unroll
    for (int t = 0; t < 16; ++t) {
        const uint32_t a0 = (uint32_t)idxB[j0 + t * 32 + rloc[0]];
        const uint32_t a1 = (uint32_t)idxB[j0 + t * 32 + rloc[1]];
        g_pk[t] = (a0 & 0xFFFFu) | (a1 << 16);
    }

    // ---- yy table for this j-quarter, once per block (2 gathers/thread) ----
#pragma unroll
    for (int t = 0; t < 2; ++t) {
        const int jj = t * 256 + tid;
        yyL[jj] = xx[idxB[j0 + jj]];
    }

    // ---- A fragments: row i0+w*64+si*16+lane15, k0 = quad*32 + s*128 ----
    // Sign-flipped so that (with A-scale = 2^1) MFMA accumulates -2*x.y.
    Frag8 A_reg[4][2];
#pragma unroll
    for (int si = 0; si < 4; ++si) {
        const int gi = idxA[i0 + w * 64 + si * 16 + lane15];
        const char* rb = S8B + ((size_t)(uint32_t)gi << 8) + quad * 32;
#pragma unroll
        for (int s = 0; s < 2; ++s) {
            A_reg[si][s].q[0] = *(const uint4*)(rb + s * 128);
            A_reg[si][s].q[1] = *(const uint4*)(rb + s * 128 + 16);
            negA(A_reg[si][s]);
        }
    }

    // ---- LDS read base (uint4 index): s=0 lo chunk c0=quad*2, row=lane15;
    //      hi = ^1, s=1 = ^8 (hi ^9), ct=1 = +256.
    const int bidx0 = lane15 * 16 + ((quad * 2) ^ lane15);

    float bestv[16];
    const float binit = isNeg ? 3.4e38f : -3.4e38f;
#pragma unroll
    for (int t = 0; t < 16; ++t) bestv[t] = binit;

    // ---- prologue: issue tiles 0 and 1 (4 copies/wave) ----
#pragma unroll
    for (int t = 0; t < 2; ++t) {
        char* lb = (char*)Bt4[t] + (w * 2) * 1024;
        async_copy16(S8B + ((size_t)(g_pk[t] & 0xFFFFu) << 8) + soff[0], lb);
        async_copy16(S8B + ((size_t)(g_pk[t] >> 16) << 8) + soff[1], lb + 1024);
    }

    __syncthreads();   // one-time full drain: tiles 0,1 in LDS; yyL visible

#pragma unroll
    for (int jc = 0; jc < 16; ++jc) {
        if (jc) {
            // my copies for tile jc landed (2 newer may stay in flight);
            // barrier => everyone's copies landed AND everyone finished
            // reading buf[(jc-1)%3] (the one tile jc+2 will overwrite).
            if (jc == 15) VMCNT0(); else VMCNT2();
            __builtin_amdgcn_s_barrier();
            __builtin_amdgcn_sched_barrier(0);
        }

        // yv: LDS broadcast (same address across the quad -> conflict-free)
        const float yv0 = yyL[(jc << 5) + lane15];
        const float yv1 = yyL[(jc << 5) + 16 + lane15];

        // prefetch tile jc+2 into buf[(jc+2)%3] (read last iter by all waves)
        if (jc < 14) {
            const uint32_t pk = g_pk[jc + 2];
            char* lb = (char*)Bt4[(jc + 2) % 3] + (w * 2) * 1024;
            async_copy16(S8B + ((size_t)(pk & 0xFFFFu) << 8) + soff[0], lb);
            async_copy16(S8B + ((size_t)(pk >> 16) << 8) + soff[1], lb + 1024);
        }

        // ---- compute: 2 K-steps of 128; explicit-LDS b128 reads feed 16
        //      MFMAs; first K-step carries yy in the C operand.
        const floatx4 yv4_0 = {yv0, yv0, yv0, yv0};
        const floatx4 yv4_1 = {yv1, yv1, yv1, yv1};
        floatx4 acc[2][4];
        {
            Frag8 bf0, bf1;
            bf0.q[0] = Bt4[jc % 3][bidx0];
            bf0.q[1] = Bt4[jc % 3][bidx0 ^ 1];
            bf1.q[0] = Bt4[jc % 3][bidx0 + 256];
            bf1.q[1] = Bt4[jc % 3][(bidx0 ^ 1) + 256];
#pragma unroll
            for (int si = 0; si < 4; ++si)
                acc[0][si] = __builtin_amdgcn_mfma_scale_f32_16x16x128_f8f6f4(
                    A_reg[si][0].v, bf0.v, yv4_0, 0, 0,
                    0, SCALE2, 0, SCALE1);
#pragma unroll
            for (int si = 0; si < 4; ++si)
                acc[1][si] = __builtin_amdgcn_mfma_scale_f32_16x16x128_f8f6f4(
                    A_reg[si][0].v, bf1.v, yv4_1, 0, 0,
                    0, SCALE2, 0, SCALE1);
        }
        {
            Frag8 bf0, bf1;
            bf0.q[0] = Bt4[jc % 3][bidx0 ^ 8];
            bf0.q[1] = Bt4[jc % 3][bidx0 ^ 9];
            bf1.q[0] = Bt4[jc % 3][(bidx0 ^ 8) + 256];
            bf1.q[1] = Bt4[jc % 3][(bidx0 ^ 9) + 256];
#pragma unroll
            for (int si = 0; si < 4; ++si)
                acc[0][si] = __builtin_amdgcn_mfma_scale_f32_16x16x128_f8f6f4(
                    A_reg[si][1].v, bf0.v, acc[0][si], 0, 0,
                    0, SCALE2, 0, SCALE1);
#pragma unroll
            for (int si = 0; si < 4; ++si)
                acc[1][si] = __builtin_amdgcn_mfma_scale_f32_16x16x128_f8f6f4(
                    A_reg[si][1].v, bf1.v, acc[1][si], 0, 0,
                    0, SCALE2, 0, SCALE1);
        }

        // ---- epilogue: acc already = yy-2xy. enc = (bits&~2047)|j ----
        const uint32_t jb0 = (uint32_t)((j0 + (jc << 5)) | lane15);
        const uint32_t jb1 = jb0 | 16u;
#pragma unroll
        for (int si = 0; si < 4; ++si)
#pragma unroll
            for (int r = 0; r < 4; ++r) {
                const float e0 = __uint_as_float(
                    (__float_as_uint(acc[0][si][r]) & 0xFFFFF800u) | jb0);
                const float e1 = __uint_as_float(
                    (__float_as_uint(acc[1][si][r]) & 0xFFFFF800u) | jb1);
                const int slot = si * 4 + r;
                bestv[slot] = isNeg ? fminf(fminf(bestv[slot], e0), e1)
                                    : fmaxf(fmaxf(bestv[slot], e0), e1);
            }
    }

    // ---- reduce over the 16 column-lanes (index rides in the bits) ----
#pragma unroll
    for (int slot = 0; slot < 16; ++slot) {
#pragma unroll
        for (int off = 1; off < 16; off <<= 1) {
            const float ov = __shfl_xor(bestv[slot], off);
            bestv[slot] = isNeg ? fminf(bestv[slot], ov) : fmaxf(bestv[slot], ov);
        }
    }
    // ---- merge across j-quarters: monotone-mapped key + device atomics ----
    if (lane15 == 0) {
#pragma unroll
        for (int si = 0; si < 4; ++si)
#pragma unroll
            for (int r = 0; r < 4; ++r) {
                const int row = w * 64 + si * 16 + quad * 4 + r;
                const uint32_t u = __float_as_uint(bestv[si * 4 + r]);
                const uint32_t key = (u & 0x80000000u) ? ~u : (u | 0x80000000u);
                if (isNeg) atomicMin(&outKey[i0 + row], key);
                else       atomicMax(&outKey[i0 + row], key);
            }
    }
}

// ------- Kernel 3: per-anchor pdist from fp8 table (16 lanes/anchor) --------
#define ACC16(UA, UP, UN)                                                     \
    {                                                                         \
        float xa, d;                                                          \
        xa = __builtin_amdgcn_cvt_f32_fp8((int)(UA), 0);                      \
        d = xa - __builtin_amdgcn_cvt_f32_fp8((int)(UP), 0); dp += d * d;     \
        d = xa - __builtin_amdgcn_cvt_f32_fp8((int)(UN), 0); dn += d * d;     \
        xa = __builtin_amdgcn_cvt_f32_fp8((int)(UA), 1);                      \
        d = xa - __builtin_amdgcn_cvt_f32_fp8((int)(UP), 1); dp += d * d;     \
        d = xa - __builtin_amdgcn_cvt_f32_fp8((int)(UN), 1); dn += d * d;     \
        xa = __builtin_amdgcn_cvt_f32_fp8((int)(UA), 2);                      \
        d = xa - __builtin_amdgcn_cvt_f32_fp8((int)(UP), 2); dp += d * d;     \
        d = xa - __builtin_amdgcn_cvt_f32_fp8((int)(UN), 2); dn += d * d;     \
        xa = __builtin_amdgcn_cvt_f32_fp8((int)(UA), 3);                      \
        d = xa - __builtin_amdgcn_cvt_f32_fp8((int)(UP), 3); dp += d * d;     \
        d = xa - __builtin_amdgcn_cvt_f32_fp8((int)(UN), 3); dn += d * d;     \
    }

__global__ __launch_bounds__(256) void loss_k(
        const unsigned int* __restrict__ S8,
        const int* __restrict__ pos_idx,
        const int* __restrict__ neg_idx,
        const unsigned int* __restrict__ hp,
        const unsigned int* __restrict__ hn,
        float* __restrict__ terms) {
    const int tid    = threadIdx.x;
    const int lane15 = tid & 15;
    const int grp    = tid >> 4;               // 0..15: anchor group in block
    const int a      = blockIdx.x * 16 + grp;  // 2048%16==0 -> one class/block
    const int k      = a >> 11;
    const int i      = a & 2047;
    const int* pidx = pos_idx + (k << 11);
    const int* nidx = neg_idx + (k << 11);
    const unsigned int kp = hp[a], kn = hn[a];
    const int jp = (int)((kp & 0x80000000u) ? (kp & 2047u) : ((~kp) & 2047u));
    const int jn = (int)((kn & 0x80000000u) ? (kn & 2047u) : ((~kn) & 2047u));
    const int ga = pidx[i];
    const int gp = pidx[jp];
    const int gn = nidx[jn];

    const char* S8B = (const char*)S8;
    const uint4 va = *(const uint4*)(S8B + ((size_t)(uint32_t)ga << 8) + lane15 * 16);
    const uint4 vp = *(const uint4*)(S8B + ((size_t)(uint32_t)gp << 8) + lane15 * 16);
    const uint4 vn = *(const uint4*)(S8B + ((size_t)(uint32_t)gn << 8) + lane15 * 16);

    float dp = 0.f, dn = 0.f;
    ACC16(va.x, vp.x, vn.x)
    ACC16(va.y, vp.y, vn.y)
    ACC16(va.z, vp.z, vn.z)
    ACC16(va.w, vp.w, vn.w)

#pragma unroll
    for (int off = 1; off < 16; off <<= 1) {   // xor stays within 16-lane group
        dp += __shfl_xor(dp, off);
        dn += __shfl_xor(dn, off);
    }
    if (lane15 == 0) {
        const float d_p = sqrtf(fmaxf(dp, 0.f) + EPS_D);
        const float d_n = sqrtf(fmaxf(dn, 0.f) + EPS_D);
        terms[a] = fmaxf(MARGIN_F + d_p - d_n, 0.f);
    }
}

// ---------------- Kernel 4: final reduction (sum of class means) ------------
// 40 blocks (single block was a ~10 us serialized tail). One atomicAdd per
// block (40 same-line atomics ~0.3 us; NOT 2560 like R18 which cost +20 us).
__global__ __launch_bounds__(1024) void reduce_k(
        const float* __restrict__ terms, float* __restrict__ out) {
    __shared__ float red[1024];
    const int tid = threadIdx.x;
    red[tid] = terms[blockIdx.x * 1024 + tid];   // 40*1024 == 40960 exactly
    __syncthreads();
    for (int off = 512; off; off >>= 1) {
        if (tid < off) red[tid] += red[tid + off];
        __syncthreads();
    }
    if (tid == 0) atomicAdd(out, red[0] * (1.0f / (float)P_POS));
}

extern "C" void kernel_launch(void* const* d_in, const int* in_sizes, int n_in,
                              void* d_out, int out_size, void* d_ws, size_t ws_size,
                              hipStream_t stream) {
    const float* feat    = (const float*)d_in[0];
    const int*   pos_idx = (const int*)d_in[1];
    const int*   neg_idx = (const int*)d_in[2];

    char* ws = (char*)d_ws;
    unsigned int* S8 = (unsigned int*)ws;                     // 16 MiB fp8 table
    float*        xx = (float*)(ws + 16777216);               // 256 KiB norms
    unsigned int* hp = (unsigned int*)(ws + 17039360);        // 160 KiB keys
    unsigned int* hn = (unsigned int*)(ws + 17203200);        // 160 KiB keys
    float*     terms = (float*)(ws + 17367040);               // 160 KiB

    sigmoid_norm_k<<<M_ROWS / 4, 256, 0, stream>>>(feat, S8, xx, hp, hn,
                                                   (float*)d_out);

    select_k<<<32 * 40, 256, 0, stream>>>(S8, xx, pos_idx, neg_idx, hp, hn);

    loss_k<<<(K_CLS * P_POS) / 16, 256, 0, stream>>>(S8, pos_idx, neg_idx, hp, hn, terms);

    reduce_k<<<40, 1024, 0, stream>>>(terms, (float*)d_out);
}